// Round 11
// baseline (128.540 us; speedup 1.0000x reference)
//
#include <hip/hip_runtime.h>
#include <cmath>

// Conductance-based LIF scan: T=512 steps, N=65536 neurons.
// R10 = R9 (zero-barrier async self-staging, store-order-robust counted
// vmcnt) + dwordx4 PREFETCH-TO-L2 "touch" loads. Hypothesis: the HBM fetch
// path at 1 wave/SIMD is limited by outstanding-request WIDTH (scalar dword
// = 256B/instr); touches fetch 1KB/instr ~24 steps ahead into L2 via
// global_load_lds size=16 aimed at a never-read LDS scratch (no VGPR
// writeback -> no compiler-inserted wait; memory side effect -> no DCE).
// The dword refills then hit L2 (~200cy) instead of HBM (~900cy).
// Each wave touches step t0+24+wid (clamped to 511), all 3 arrays, for the
// whole block's 256-neuron row -> uniform 3 touch instrs/wave/group.
//
// Robust wait rule (validated R9): before consuming batch B wait
// vmcnt(K), K = #LOADS issued after B's last load (loads retire in order
// among themselves; no assumption on store retirement order).
// Issue order: prologue B0..B3,T,T; per group: [3 touches][12 refills].
//   g0..g3: K = 42,45,48,51; steady g4..g123: K = 45;
//   epilogue g124..g127: K = 45,30,15,0.
//
// Numerics identical to R5/R7/R9 (passed, absmax 0.00390625):
// FMA-contracted, rcp-div, __expf. gA == 0 (ADAPT_INC==0), elided.

__device__ __forceinline__ void gload_lds4(const float* g, float* l) {
    __builtin_amdgcn_global_load_lds(
        (const __attribute__((address_space(1))) unsigned int*)(const void*)g,
        (__attribute__((address_space(3))) unsigned int*)(void*)l,
        4, 0, 0);
}
__device__ __forceinline__ void gload_lds16(const float* g, float* l) {
    __builtin_amdgcn_global_load_lds(
        (const __attribute__((address_space(1))) unsigned int*)(const void*)g,
        (__attribute__((address_space(3))) unsigned int*)(void*)l,
        16, 0, 0);
}

#define WAITV(n) asm volatile("s_waitcnt vmcnt(" #n ")" ::: "memory")

__global__ __launch_bounds__(256, 1) void lif_scan(
    const float* __restrict__ g_exc,
    const float* __restrict__ g_inh,
    const float* __restrict__ noise,
    const float* __restrict__ v_th,
    const float* __restrict__ tau_ref,
    float* __restrict__ out_spk,   // d_out[0 .. T*N)
    float* __restrict__ out_mem,   // d_out[T*N .. 2*T*N)
    int N, int T,
    float cGE, float cGI, float cALPHA, float cSIGMA)
{
    __shared__ float smem[16][3][256];     // ring: 16 slots = 4 batches, 48 KiB
    __shared__ float tscratch[4][256];     // touch dump, never read, 4 KiB

    const int tid  = threadIdx.x;
    const int lane = tid & 63;
    const int wid  = tid >> 6;
    const int wq   = wid << 6;                  // wave's LDS quarter base
    const int n    = blockIdx.x * 256 + tid;

    const float vth = v_th[n];
    const float trf = tau_ref[n];

    float v = 0.f, gE = 0.f, gI = 0.f, ref = 0.f, ou = 0.f;

    // touch: pull the block's full 256-neuron row of all 3 arrays at step
    // ts into L2. 64 lanes x 16B = 1KB/instr; dest = wave's scratch.
    auto touch3 = [&](int ts) {
        const size_t base = (size_t)ts * (size_t)N
                          + (size_t)blockIdx.x * 256 + (size_t)(lane * 4);
        float* dst = &tscratch[wid][0];
        gload_lds16(g_exc + base, dst);
        gload_lds16(g_inh + base, dst);
        gload_lds16(noise + base, dst);
    };

    // stage steps t0..t0+3 into ring slots sb..sb+3 (12 dword async loads)
    auto issueB = [&](int t0, int sb) {
        #pragma unroll
        for (int k = 0; k < 4; ++k) {
            const size_t row = (size_t)(t0 + k) * (size_t)N + (size_t)n;
            gload_lds4(g_exc + row, &smem[sb + k][0][wq]);
            gload_lds4(g_inh + row, &smem[sb + k][1][wq]);
            gload_lds4(noise + row, &smem[sb + k][2][wq]);
        }
    };

    auto step = [&](float ge_in, float gi_in, float z, int tt) {
        gE = __builtin_fmaf(gE, cGE, ge_in);
        gI = __builtin_fmaf(gI, cGI, gi_in);

        const float gt  = 1.0f + gE + gI;
        const float num = __builtin_fmaf(gI, -0.5f, gE * 3.0f);
        const float vinf = num * __builtin_amdgcn_rcpf(gt);

        const float decay = __expf(-0.05f * gt);

        v = __builtin_fmaf(v - vinf, decay, vinf);

        ou = __builtin_fmaf(ou, cALPHA, cSIGMA * z);
        v = v + ou;

        const bool in_ref = (ref > 0.0f);
        const bool spike  = (v >= vth) && (!in_ref);
        v = (in_ref || spike) ? 0.0f : v;
        ref = spike ? trf : fmaxf(ref - 1.0f, 0.0f);

        const size_t off = (size_t)tt * (size_t)N + (size_t)n;
        __builtin_nontemporal_store(spike ? 1.0f : 0.0f, out_spk + off);
        __builtin_nontemporal_store(v, out_mem + off);
    };

    // one 4-step group: read slots sb..sb+3; touch t0+24+wid; refill slots
    // for t0+16; compute 4 steps (+8 NT stores)
    auto group = [&](int t0, int sb, bool issue) {
        float vals[12];
        #pragma unroll
        for (int k = 0; k < 4; ++k) {
            vals[k * 3 + 0] = smem[sb + k][0][tid];
            vals[k * 3 + 1] = smem[sb + k][1][tid];
            vals[k * 3 + 2] = smem[sb + k][2][tid];
        }
        // slot data in VGPRs before its refill is issued
        asm volatile("s_waitcnt lgkmcnt(0)" ::: "memory");
        if (issue) {
            int ts = t0 + 24 + wid; ts = ts < 511 ? ts : 511;  // clamp in-bounds
            touch3(ts);            // touches issued BEFORE refills (older)
            issueB(t0 + 16, sb);
        }
        #pragma unroll
        for (int k = 0; k < 4; ++k)
            step(vals[k * 3 + 0], vals[k * 3 + 1], vals[k * 3 + 2], t0 + k);
    };

    // prologue: 4 batches in flight + touches for their refill targets
    issueB(0, 0);
    issueB(4, 4);
    issueB(8, 8);
    issueB(12, 12);
    touch3(16 + wid);
    touch3(20 + wid);

    WAITV(42); group(0,  0,  true);   // younger than B0: 36 + T6
    WAITV(45); group(4,  4,  true);   // 24 + 6 + 15
    WAITV(48); group(8,  8,  true);   // 12 + 6 + 30
    WAITV(51); group(12, 12, true);   // 6 + 45
    // steady: K = 3 groups x (3 touches + 12 refills) = 45
    for (int p = 1; p <= 30; ++p) {
        WAITV(45); group(16 * p,      0,  true);
        WAITV(45); group(16 * p + 4,  4,  true);
        WAITV(45); group(16 * p + 8,  8,  true);
        WAITV(45); group(16 * p + 12, 12, true);
    }
    // epilogue groups 124..127 (no issue): K = 45, 30, 15, 0
    WAITV(45); group(496, 0,  false);
    WAITV(30); group(500, 4,  false);
    WAITV(15); group(504, 8,  false);
    WAITV(0);  group(508, 12, false);
}

extern "C" void kernel_launch(void* const* d_in, const int* in_sizes, int n_in,
                              void* d_out, int out_size, void* d_ws, size_t ws_size,
                              hipStream_t stream) {
    const float* g_exc   = (const float*)d_in[0];
    const float* g_inh   = (const float*)d_in[1];
    const float* noise   = (const float*)d_in[2];
    const float* v_th    = (const float*)d_in[3];
    const float* tau_ref = (const float*)d_in[4];

    const int N = in_sizes[3];            // 65536
    const int T = in_sizes[0] / N;        // 512

    float* out_spk = (float*)d_out;
    float* out_mem = (float*)d_out + (size_t)T * (size_t)N;

    // Constants computed in double exactly as the Python reference does.
    const double ge_decay = exp(-1.0 / 5.0);
    const double gi_decay = exp(-1.0 / 10.0);
    const double ou_alpha = exp(-1.0 / 5.0);
    const double ou_sigma = 0.02 * sqrt(1.0 - ou_alpha * ou_alpha);

    const int block = 256;
    const int grid = (N + block - 1) / block;   // 256 blocks = 1024 waves
    lif_scan<<<grid, block, 0, stream>>>(
        g_exc, g_inh, noise, v_th, tau_ref, out_spk, out_mem,
        N, T,
        (float)ge_decay, (float)gi_decay, (float)ou_alpha, (float)ou_sigma);
}